// Round 2
// baseline (6069.246 us; speedup 1.0000x reference)
//
#include <hip/hip_runtime.h>

typedef __attribute__((ext_vector_type(8))) short short8;
typedef __attribute__((ext_vector_type(4))) float f32x4;

// ---------- helpers ----------
__device__ __forceinline__ unsigned short f2bu(float x) {
  unsigned int u = __float_as_uint(x);
  u += 0x7fffu + ((u >> 16) & 1u);
  return (unsigned short)(u >> 16);
}
__device__ __forceinline__ unsigned int pk2(float a, float b) {
  return (unsigned int)f2bu(a) | ((unsigned int)f2bu(b) << 16);
}
__device__ __forceinline__ void gload_lds16(const void* g, void* l) {
  __builtin_amdgcn_global_load_lds((const __attribute__((address_space(1))) unsigned int*)g,
                                   (__attribute__((address_space(3))) unsigned int*)l, 16, 0, 0);
}

// ---------- cast & concat ----------
__global__ void cast_concat_kernel(const float* __restrict__ Mf,
                                   const float* __restrict__ DTf,
                                   const float* __restrict__ Df,
                                   unsigned short* __restrict__ ins) {
  size_t idx = (size_t)blockIdx.x * blockDim.x + threadIdx.x;
  size_t e0 = idx * 8;
  size_t m = e0 >> 10;
  int c = (int)(e0 & 1023);
  const float* src;
  if (c < 256)      src = Mf  + m * 256 + c;
  else if (c < 512) src = DTf + m * 256 + (c - 256);
  else              src = Df  + m * 512 + (c - 512);
  float4 f0 = reinterpret_cast<const float4*>(src)[0];
  float4 f1 = reinterpret_cast<const float4*>(src)[1];
  uint4 o;
  o.x = pk2(f0.x, f0.y); o.y = pk2(f0.z, f0.w);
  o.z = pk2(f1.x, f1.y); o.w = pk2(f1.z, f1.w);
  *reinterpret_cast<uint4*>(ins + e0) = o;
}

__global__ void cast_w_kernel(const float* __restrict__ in, unsigned short* __restrict__ out, int n8) {
  int idx = blockIdx.x * blockDim.x + threadIdx.x;
  if (idx >= n8) return;
  const float* src = in + (size_t)idx * 8;
  float4 f0 = reinterpret_cast<const float4*>(src)[0];
  float4 f1 = reinterpret_cast<const float4*>(src)[1];
  uint4 o;
  o.x = pk2(f0.x, f0.y); o.y = pk2(f0.z, f0.w);
  o.z = pk2(f1.x, f1.y); o.w = pk2(f1.z, f1.w);
  *reinterpret_cast<uint4*>(out + (size_t)idx * 8) = o;
}

// ---------- GEMM (m97 structure, unchanged) ----------
template <int RELU, typename TOUT>
__global__ __launch_bounds__(256) void gemm_bt_kernel(const unsigned short* __restrict__ A,
                                                      const unsigned short* __restrict__ Bt,
                                                      TOUT* __restrict__ C,
                                                      int M, int N, int K) {
  __shared__ unsigned short As[128 * 32];
  __shared__ unsigned short Bs[128 * 32];
  const int tid = threadIdx.x;
  const int l = tid & 63, w = tid >> 6;
  const int lr = l & 15, lg = l >> 4;
  const int wm = w >> 1, wn = w & 1;
  const int tiles_n = N >> 7;
  const int tm = blockIdx.x / tiles_n, tn = blockIdx.x % tiles_n;
  const int bm0 = tm << 7, bn0 = tn << 7;

  f32x4 acc[4][4] = {};

  for (int kt = 0; kt < K; kt += 32) {
#pragma unroll
    for (int i = 0; i < 2; ++i) {
      int ch = tid + (i << 8);
      int row = ch >> 2, cc = ch & 3;
      const unsigned short* ga = A + (size_t)(bm0 + row) * K + kt + cc * 8;
      const unsigned short* gb = Bt + (size_t)(bn0 + row) * K + kt + cc * 8;
      unsigned short* la = As + ((size_t)((i << 8) + (w << 6))) * 8;
      unsigned short* lb = Bs + ((size_t)((i << 8) + (w << 6))) * 8;
      gload_lds16(ga, la);
      gload_lds16(gb, lb);
    }
    __syncthreads();
    short8 af[4], bf[4];
#pragma unroll
    for (int mi = 0; mi < 4; ++mi)
      af[mi] = *reinterpret_cast<const short8*>(As + (wm * 64 + mi * 16 + lr) * 32 + lg * 8);
#pragma unroll
    for (int ni = 0; ni < 4; ++ni)
      bf[ni] = *reinterpret_cast<const short8*>(Bs + (wn * 64 + ni * 16 + lr) * 32 + lg * 8);
#pragma unroll
    for (int mi = 0; mi < 4; ++mi)
#pragma unroll
      for (int ni = 0; ni < 4; ++ni)
        acc[mi][ni] = __builtin_amdgcn_mfma_f32_16x16x32_bf16(af[mi], bf[ni], acc[mi][ni], 0, 0, 0);
    __syncthreads();
  }

#pragma unroll
  for (int mi = 0; mi < 4; ++mi)
#pragma unroll
    for (int ni = 0; ni < 4; ++ni)
#pragma unroll
      for (int r = 0; r < 4; ++r) {
        int row = bm0 + wm * 64 + mi * 16 + lg * 4 + r;
        int col = bn0 + wn * 64 + ni * 16 + lr;
        float v = acc[mi][ni][r];
        if (RELU) v = fmaxf(v, 0.f);
        if constexpr (sizeof(TOUT) == 2) {
          reinterpret_cast<unsigned short*>(C)[(size_t)row * N + col] = f2bu(v);
        } else {
          C[(size_t)row * N + col] = v;
        }
      }
}

// ---------- recurrence: explicit 8-region rolling pipeline ----------
// 16 blocks x 16 rows; 512 threads = 8 waves, wave w owns 64 output cols.
// W streamed from L2 in 8 half-jt batches/step through 4 rotating 8-frag reg
// buffers (128 VGPR); next step's first 2 batches issued before the barrier so
// vmcnt never drains. amdgpu_waves_per_eu(2,2) pins the 256-VGPR budget.
#define SB() __builtin_amdgcn_sched_barrier(0)

#define ISSUE_W(buf, jt, half)                                                 \
  _Pragma("unroll") for (int q = 0; q < 8; ++q) buf[q] =                       \
      *reinterpret_cast<const short8*>(wlane + (size_t)(jt)*16 * 512 +         \
                                       ((half)*8 + q) * 32);

#define MFMA8(buf, half, jt)                                                   \
  _Pragma("unroll") for (int q = 0; q < 8; ++q) acc[jt] =                      \
      __builtin_amdgcn_mfma_f32_16x16x32_bf16(a[(half)*8 + q], buf[q],         \
                                              acc[jt], 0, 0, 0);

__global__ __launch_bounds__(512, 2) __attribute__((amdgpu_waves_per_eu(2, 2)))
void recurrence_kernel(const float* __restrict__ x0,
                       const float* __restrict__ G,
                       const unsigned short* W,   // no restrict: block LICM of W loads
                       float* X, float* Y) {
  __shared__ char xls[2][16 * 1024];
  const int tid = threadIdx.x;
  const int l = tid & 63, w = tid >> 6;
  const int lr = l & 15, lg = l >> 4;
  const int r0 = blockIdx.x << 4;
  const int jb = w << 6;

  // init x into buf 0
  {
    int row = tid >> 5;
    int kc = (tid & 31) << 4;
    const float* src = x0 + (size_t)(r0 + row) * 512 + kc;
    float4 f0 = reinterpret_cast<const float4*>(src)[0];
    float4 f1 = reinterpret_cast<const float4*>(src)[1];
    float4 f2 = reinterpret_cast<const float4*>(src)[2];
    float4 f3 = reinterpret_cast<const float4*>(src)[3];
    uint4 o0, o1;
    o0.x = pk2(f0.x, f0.y); o0.y = pk2(f0.z, f0.w); o0.z = pk2(f1.x, f1.y); o0.w = pk2(f1.z, f1.w);
    o1.x = pk2(f2.x, f2.y); o1.y = pk2(f2.z, f2.w); o1.z = pk2(f3.x, f3.y); o1.w = pk2(f3.z, f3.w);
    int swz = (row & 7) << 4;
    *reinterpret_cast<uint4*>(xls[0] + row * 1024 + ((kc * 2) ^ swz)) = o0;
    *reinterpret_cast<uint4*>(xls[0] + row * 1024 + ((kc * 2 + 16) ^ swz)) = o1;
  }
  __syncthreads();

  const unsigned short* wlane = W + (size_t)(jb + lr) * 512 + lg * 8;
  const int swzA = (lr & 7) << 4;

  short8 bP[8], bQ[8], bR[8], bS[8];
  // pre-loop: h0 (jt0,half0) -> P, h1 (jt0,half1) -> Q
  ISSUE_W(bP, 0, 0);
  ISSUE_W(bQ, 0, 1);

  int cur = 0;
  for (int t = 0; t < 256; ++t) {
    const float* Gt = G + ((size_t)t * 256 + r0) * 512;
    float* Xt = X + ((size_t)t * 256 + r0) * 512;

    // prologue: a-frags from LDS, h2 -> R, G prefetch
    short8 a[16];
#pragma unroll
    for (int kk = 0; kk < 16; ++kk) {
      int kb = kk * 64 + lg * 16;
      a[kk] = *reinterpret_cast<const short8*>(xls[cur] + lr * 1024 + (kb ^ swzA));
    }
    ISSUE_W(bR, 1, 0);
    float g[4][4];
#pragma unroll
    for (int jt = 0; jt < 4; ++jt)
#pragma unroll
      for (int r = 0; r < 4; ++r)
        g[jt][r] = Gt[(lg * 4 + r) * 512 + jb + jt * 16 + lr];
    SB();

    f32x4 acc[4] = {};
    // h0: mfma(P = jt0/h0), issue S <- h3
    ISSUE_W(bS, 1, 1); SB(); MFMA8(bP, 0, 0); SB();
    // h1: mfma(Q = jt0/h1), issue P <- h4
    ISSUE_W(bP, 2, 0); SB(); MFMA8(bQ, 1, 0); SB();
    // h2: mfma(R = jt1/h0), issue Q <- h5
    ISSUE_W(bQ, 2, 1); SB(); MFMA8(bR, 0, 1); SB();
    // h3: mfma(S = jt1/h1), issue R <- h6
    ISSUE_W(bR, 3, 0); SB(); MFMA8(bS, 1, 1); SB();
    // h4: mfma(P = jt2/h0), issue S <- h7
    ISSUE_W(bS, 3, 1); SB(); MFMA8(bP, 0, 2); SB();
    // h5: mfma(Q = jt2/h1), issue P <- h0 (next step)
    ISSUE_W(bP, 0, 0); SB(); MFMA8(bQ, 1, 2); SB();
    // h6: mfma(R = jt3/h0), issue Q <- h1 (next step)
    ISSUE_W(bQ, 0, 1); SB(); MFMA8(bR, 0, 3); SB();
    // h7: mfma(S = jt3/h1)
    MFMA8(bS, 1, 3); SB();

    // epilogue
    char* xw = xls[cur ^ 1];
#pragma unroll
    for (int jt = 0; jt < 4; ++jt)
#pragma unroll
      for (int r = 0; r < 4; ++r) {
        float v = fmaxf(g[jt][r] + acc[jt][r], 0.f);
        int i = lg * 4 + r;
        int j = jb + jt * 16 + lr;
        Xt[(size_t)i * 512 + j] = v;
        *reinterpret_cast<unsigned short*>(xw + i * 1024 + ((j * 2) ^ ((i & 7) << 4))) = f2bu(v);
        if (j == 511) Y[t * 256 + r0 + i] = v;
      }
    __syncthreads();
    cur ^= 1;
  }
}

// ---------- launch ----------
extern "C" void kernel_launch(void* const* d_in, const int* in_sizes, int n_in,
                              void* d_out, int out_size, void* d_ws, size_t ws_size,
                              hipStream_t stream) {
  const float* x0   = (const float*)d_in[0];
  const float* Mf   = (const float*)d_in[1];
  const float* DTf  = (const float*)d_in[2];
  const float* Df   = (const float*)d_in[3];
  const float* Wih0 = (const float*)d_in[4];
  const float* Wih1 = (const float*)d_in[6];
  const float* Whh1 = (const float*)d_in[7];

  char* ws = (char*)d_ws;
  unsigned short* ins = (unsigned short*)(ws);
  unsigned short* H   = (unsigned short*)(ws + 134217728ULL);
  unsigned short* w0b = (unsigned short*)(ws + 268435456ULL);
  unsigned short* w1b = (unsigned short*)(ws + 270532608ULL);
  unsigned short* whb = (unsigned short*)(ws + 271581184ULL);
  float* G = (float*)(ws);   // aliases ins (dead after GEMM1)

  cast_concat_kernel<<<32768, 256, 0, stream>>>(Mf, DTf, Df, ins);
  cast_w_kernel<<<512, 256, 0, stream>>>(Wih0, w0b, 131072);
  cast_w_kernel<<<256, 256, 0, stream>>>(Wih1, w1b, 65536);
  cast_w_kernel<<<128, 256, 0, stream>>>(Whh1, whb, 32768);

  gemm_bt_kernel<1, unsigned short><<<(65536 / 128) * (1024 / 128), 256, 0, stream>>>(
      ins, w0b, H, 65536, 1024, 1024);
  gemm_bt_kernel<0, float><<<(65536 / 128) * (512 / 128), 256, 0, stream>>>(
      H, w1b, G, 65536, 512, 1024);

  float* X = (float*)d_out;
  float* Y = X + 33554432;
  recurrence_kernel<<<16, 512, 0, stream>>>(x0, G, whb, X, Y);
}

// Round 3
// 3531.063 us; speedup vs baseline: 1.7188x; 1.7188x over previous
//
#include <hip/hip_runtime.h>

typedef __attribute__((ext_vector_type(8))) short short8;
typedef __attribute__((ext_vector_type(4))) float f32x4;

// ---------- helpers ----------
__device__ __forceinline__ unsigned short f2bu(float x) {
  unsigned int u = __float_as_uint(x);
  u += 0x7fffu + ((u >> 16) & 1u);
  return (unsigned short)(u >> 16);
}
__device__ __forceinline__ unsigned int pk2(float a, float b) {
  return (unsigned int)f2bu(a) | ((unsigned int)f2bu(b) << 16);
}
__device__ __forceinline__ void gload_lds16(const void* g, void* l) {
  __builtin_amdgcn_global_load_lds((const __attribute__((address_space(1))) unsigned int*)g,
                                   (__attribute__((address_space(3))) unsigned int*)l, 16, 0, 0);
}

// ---------- cast & concat ----------
__global__ void cast_concat_kernel(const float* __restrict__ Mf,
                                   const float* __restrict__ DTf,
                                   const float* __restrict__ Df,
                                   unsigned short* __restrict__ ins) {
  size_t idx = (size_t)blockIdx.x * blockDim.x + threadIdx.x;
  size_t e0 = idx * 8;
  size_t m = e0 >> 10;
  int c = (int)(e0 & 1023);
  const float* src;
  if (c < 256)      src = Mf  + m * 256 + c;
  else if (c < 512) src = DTf + m * 256 + (c - 256);
  else              src = Df  + m * 512 + (c - 512);
  float4 f0 = reinterpret_cast<const float4*>(src)[0];
  float4 f1 = reinterpret_cast<const float4*>(src)[1];
  uint4 o;
  o.x = pk2(f0.x, f0.y); o.y = pk2(f0.z, f0.w);
  o.z = pk2(f1.x, f1.y); o.w = pk2(f1.z, f1.w);
  *reinterpret_cast<uint4*>(ins + e0) = o;
}

__global__ void cast_w_kernel(const float* __restrict__ in, unsigned short* __restrict__ out, int n8) {
  int idx = blockIdx.x * blockDim.x + threadIdx.x;
  if (idx >= n8) return;
  const float* src = in + (size_t)idx * 8;
  float4 f0 = reinterpret_cast<const float4*>(src)[0];
  float4 f1 = reinterpret_cast<const float4*>(src)[1];
  uint4 o;
  o.x = pk2(f0.x, f0.y); o.y = pk2(f0.z, f0.w);
  o.z = pk2(f1.x, f1.y); o.w = pk2(f1.z, f1.w);
  *reinterpret_cast<uint4*>(out + (size_t)idx * 8) = o;
}

// ---------- GEMM (m97 structure, unchanged) ----------
template <int RELU, typename TOUT>
__global__ __launch_bounds__(256) void gemm_bt_kernel(const unsigned short* __restrict__ A,
                                                      const unsigned short* __restrict__ Bt,
                                                      TOUT* __restrict__ C,
                                                      int M, int N, int K) {
  __shared__ unsigned short As[128 * 32];
  __shared__ unsigned short Bs[128 * 32];
  const int tid = threadIdx.x;
  const int l = tid & 63, w = tid >> 6;
  const int lr = l & 15, lg = l >> 4;
  const int wm = w >> 1, wn = w & 1;
  const int tiles_n = N >> 7;
  const int tm = blockIdx.x / tiles_n, tn = blockIdx.x % tiles_n;
  const int bm0 = tm << 7, bn0 = tn << 7;

  f32x4 acc[4][4] = {};

  for (int kt = 0; kt < K; kt += 32) {
#pragma unroll
    for (int i = 0; i < 2; ++i) {
      int ch = tid + (i << 8);
      int row = ch >> 2, cc = ch & 3;
      const unsigned short* ga = A + (size_t)(bm0 + row) * K + kt + cc * 8;
      const unsigned short* gb = Bt + (size_t)(bn0 + row) * K + kt + cc * 8;
      unsigned short* la = As + ((size_t)((i << 8) + (w << 6))) * 8;
      unsigned short* lb = Bs + ((size_t)((i << 8) + (w << 6))) * 8;
      gload_lds16(ga, la);
      gload_lds16(gb, lb);
    }
    __syncthreads();
    short8 af[4], bf[4];
#pragma unroll
    for (int mi = 0; mi < 4; ++mi)
      af[mi] = *reinterpret_cast<const short8*>(As + (wm * 64 + mi * 16 + lr) * 32 + lg * 8);
#pragma unroll
    for (int ni = 0; ni < 4; ++ni)
      bf[ni] = *reinterpret_cast<const short8*>(Bs + (wn * 64 + ni * 16 + lr) * 32 + lg * 8);
#pragma unroll
    for (int mi = 0; mi < 4; ++mi)
#pragma unroll
      for (int ni = 0; ni < 4; ++ni)
        acc[mi][ni] = __builtin_amdgcn_mfma_f32_16x16x32_bf16(af[mi], bf[ni], acc[mi][ni], 0, 0, 0);
    __syncthreads();
  }

#pragma unroll
  for (int mi = 0; mi < 4; ++mi)
#pragma unroll
    for (int ni = 0; ni < 4; ++ni)
#pragma unroll
      for (int r = 0; r < 4; ++r) {
        int row = bm0 + wm * 64 + mi * 16 + lg * 4 + r;
        int col = bn0 + wn * 64 + ni * 16 + lr;
        float v = acc[mi][ni][r];
        if (RELU) v = fmaxf(v, 0.f);
        if constexpr (sizeof(TOUT) == 2) {
          reinterpret_cast<unsigned short*>(C)[(size_t)row * N + col] = f2bu(v);
        } else {
          C[(size_t)row * N + col] = v;
        }
      }
}

// ---------- recurrence: W streamed via global_load_lds, counted-vmcnt pipeline ----------
// 16 blocks x 16 rows; 512 threads = 8 waves; wave w owns j in [64w, 64w+64).
// Per step: 16 phases of k=32. Per wave: 4 private 4KB LDS bufs; phase p reads
// buf p&3, issues DMA for phase p+3 into buf (p+3)&3 (never a live read buf ->
// race-free by construction). Counted s_waitcnt vmcnt(N); raw s_barrier per
// step (no vmcnt drain). G prefetched one full step ahead (HBM runway).
#define WAITVM(N) asm volatile("s_waitcnt vmcnt(" #N ")" ::: "memory")

#define DMA_PH(PT)                                                            \
  {                                                                           \
    char* db = wdst + ((PT)&3) * 4096;                                        \
    const unsigned short* gs = Wg + gwfix + ((PT)&15) * 32;                   \
    gload_lds16(gs, db);                                                      \
    gload_lds16(gs + 8192, db + 1024);                                        \
    gload_lds16(gs + 16384, db + 2048);                                       \
    gload_lds16(gs + 24576, db + 3072);                                       \
  }

#define PH(p, N)                                                              \
  WAITVM(N);                                                                  \
  {                                                                           \
    const char* rb = wrd + ((p)&3) * 4096;                                    \
    short8 w0 = *reinterpret_cast<const short8*>(rb);                         \
    short8 w1 = *reinterpret_cast<const short8*>(rb + 1024);                  \
    short8 w2 = *reinterpret_cast<const short8*>(rb + 2048);                  \
    short8 w3 = *reinterpret_cast<const short8*>(rb + 3072);                  \
    acc[0] = __builtin_amdgcn_mfma_f32_16x16x32_bf16(a[p], w0, acc[0], 0, 0, 0); \
    acc[1] = __builtin_amdgcn_mfma_f32_16x16x32_bf16(a[p], w1, acc[1], 0, 0, 0); \
    acc[2] = __builtin_amdgcn_mfma_f32_16x16x32_bf16(a[p], w2, acc[2], 0, 0, 0); \
    acc[3] = __builtin_amdgcn_mfma_f32_16x16x32_bf16(a[p], w3, acc[3], 0, 0, 0); \
  }                                                                           \
  DMA_PH((p) + 3)

#define GISS(GARR, TN)                                                        \
  {                                                                           \
    const float* Gn = G + ((size_t)(TN)*256 + r0) * 512;                      \
    _Pragma("unroll") for (int jt = 0; jt < 4; ++jt)                          \
        _Pragma("unroll") for (int r = 0; r < 4; ++r)                         \
            GARR[jt * 4 + r] = Gn[(lg * 4 + r) * 512 + jb + jt * 16 + lr];    \
  }

#define STEP(T, PAR, GCUR, GNXT)                                              \
  {                                                                           \
    const char* xb = smem + 131072 + (PAR)*16384;                             \
    short8 a[16];                                                             \
    _Pragma("unroll") for (int kk = 0; kk < 16; ++kk)                         \
        a[kk] = *reinterpret_cast<const short8*>(xb + lr * 1024 +             \
                                                 ((kk * 64 + lg16) ^ swzA)); \
    f32x4 acc[4] = {};                                                        \
    PH(0, 21) PH(1, 21) PH(2, 21)                                             \
    PH(3, 4) PH(4, 4) PH(5, 4) PH(6, 4) PH(7, 4) PH(8, 4)                     \
    PH(9, 4) PH(10, 4) PH(11, 4)                                              \
    PH(12, 4) GISS(GNXT, (T) + 1)                                             \
    PH(13, 20) PH(14, 20) PH(15, 20)                                          \
    float* Xt = X + ((size_t)(T)*256 + r0) * 512;                             \
    char* xw = smem + 131072 + (1 - (PAR)) * 16384;                           \
    _Pragma("unroll") for (int jt = 0; jt < 4; ++jt)                          \
        _Pragma("unroll") for (int r = 0; r < 4; ++r) {                       \
      float v = fmaxf(GCUR[jt * 4 + r] + acc[jt][r], 0.f);                    \
      int i = lg * 4 + r;                                                     \
      int j = jb + jt * 16 + lr;                                              \
      Xt[(size_t)i * 512 + j] = v;                                            \
      *reinterpret_cast<unsigned short*>(xw + i * 1024 +                      \
                                         ((j * 2) ^ ((i & 7) << 4))) = f2bu(v); \
      if (j == 511) Y[(T)*256 + r0 + i] = v;                                  \
    }                                                                         \
    asm volatile("s_waitcnt lgkmcnt(0)" ::: "memory");                        \
    __builtin_amdgcn_s_barrier();                                             \
  }

__global__ __launch_bounds__(512, 2)
void recurrence_kernel(const float* __restrict__ x0,
                       const float* __restrict__ G,
                       const unsigned short* Wg,
                       float* X, float* Y) {
  __shared__ char smem[163840];   // [0,128K): 8 waves x 4 bufs x 4KB; [128K,160K): x dbuf
  const int tid = threadIdx.x;
  const int l = tid & 63, w = tid >> 6;
  const int lr = l & 15, lg = l >> 4;
  const int lg16 = lg * 16;
  const int r0 = blockIdx.x << 4;
  const int jb = w << 6;

  // init x into x-buf 0
  {
    int row = tid >> 5;
    int kc = (tid & 31) << 4;
    const float* src = x0 + (size_t)(r0 + row) * 512 + kc;
    float4 f0 = reinterpret_cast<const float4*>(src)[0];
    float4 f1 = reinterpret_cast<const float4*>(src)[1];
    float4 f2 = reinterpret_cast<const float4*>(src)[2];
    float4 f3 = reinterpret_cast<const float4*>(src)[3];
    uint4 o0, o1;
    o0.x = pk2(f0.x, f0.y); o0.y = pk2(f0.z, f0.w); o0.z = pk2(f1.x, f1.y); o0.w = pk2(f1.z, f1.w);
    o1.x = pk2(f2.x, f2.y); o1.y = pk2(f2.z, f2.w); o1.z = pk2(f3.x, f3.y); o1.w = pk2(f3.z, f3.w);
    int swz = (row & 7) << 4;
    char* xb0 = smem + 131072;
    *reinterpret_cast<uint4*>(xb0 + row * 1024 + ((kc * 2) ^ swz)) = o0;
    *reinterpret_cast<uint4*>(xb0 + row * 1024 + ((kc * 2 + 16) ^ swz)) = o1;
  }
  __syncthreads();

  // per-lane constants
  char* wdst = smem + w * 16384;                                   // DMA dst (wave-uniform)
  const char* wrd = smem + w * 16384 + lr * 64 + ((lg ^ (lr & 3)) << 4);  // frag read base
  const int gwfix = (w * 64 + (l >> 2)) * 512 + (((l & 3) ^ ((l >> 2) & 3)) << 3);
  const int swzA = (lr & 7) << 4;

  float gA[16], gB[16];
  // prologue: DMA phases 0..2, G for t=0
  DMA_PH(0) DMA_PH(1) DMA_PH(2)
  GISS(gA, 0)

  for (int tt = 0; tt < 256; tt += 2) {
    STEP(tt, 0, gA, gB)
    STEP(tt + 1, 1, gB, gA)
  }
}

// ---------- launch ----------
extern "C" void kernel_launch(void* const* d_in, const int* in_sizes, int n_in,
                              void* d_out, int out_size, void* d_ws, size_t ws_size,
                              hipStream_t stream) {
  const float* x0   = (const float*)d_in[0];
  const float* Mf   = (const float*)d_in[1];
  const float* DTf  = (const float*)d_in[2];
  const float* Df   = (const float*)d_in[3];
  const float* Wih0 = (const float*)d_in[4];
  const float* Wih1 = (const float*)d_in[6];
  const float* Whh1 = (const float*)d_in[7];

  char* ws = (char*)d_ws;
  unsigned short* ins = (unsigned short*)(ws);
  unsigned short* H   = (unsigned short*)(ws + 134217728ULL);
  unsigned short* w0b = (unsigned short*)(ws + 268435456ULL);
  unsigned short* w1b = (unsigned short*)(ws + 270532608ULL);
  unsigned short* whb = (unsigned short*)(ws + 271581184ULL);
  float* G = (float*)(ws);   // aliases ins (dead after GEMM1)

  cast_concat_kernel<<<32768, 256, 0, stream>>>(Mf, DTf, Df, ins);
  cast_w_kernel<<<512, 256, 0, stream>>>(Wih0, w0b, 131072);
  cast_w_kernel<<<256, 256, 0, stream>>>(Wih1, w1b, 65536);
  cast_w_kernel<<<128, 256, 0, stream>>>(Whh1, whb, 32768);

  gemm_bt_kernel<1, unsigned short><<<(65536 / 128) * (1024 / 128), 256, 0, stream>>>(
      ins, w0b, H, 65536, 1024, 1024);
  gemm_bt_kernel<0, float><<<(65536 / 128) * (512 / 128), 256, 0, stream>>>(
      H, w1b, G, 65536, 512, 1024);

  float* X = (float*)d_out;
  float* Y = X + 33554432;
  recurrence_kernel<<<16, 512, 0, stream>>>(x0, G, whb, X, Y);
}

// Round 4
// 1863.178 us; speedup vs baseline: 3.2575x; 1.8952x over previous
//
#include <hip/hip_runtime.h>

typedef __attribute__((ext_vector_type(8))) short short8;
typedef __attribute__((ext_vector_type(4))) float f32x4;

// ---------- helpers ----------
__device__ __forceinline__ unsigned short f2bu(float x) {
  unsigned int u = __float_as_uint(x);
  u += 0x7fffu + ((u >> 16) & 1u);
  return (unsigned short)(u >> 16);
}
__device__ __forceinline__ unsigned int pk2(float a, float b) {
  return (unsigned int)f2bu(a) | ((unsigned int)f2bu(b) << 16);
}
__device__ __forceinline__ void gload_lds16(const void* g, void* l) {
  __builtin_amdgcn_global_load_lds((const __attribute__((address_space(1))) unsigned int*)g,
                                   (__attribute__((address_space(3))) unsigned int*)l, 16, 0, 0);
}

// ---------- cast & concat ----------
__global__ void cast_concat_kernel(const float* __restrict__ Mf,
                                   const float* __restrict__ DTf,
                                   const float* __restrict__ Df,
                                   unsigned short* __restrict__ ins) {
  size_t idx = (size_t)blockIdx.x * blockDim.x + threadIdx.x;
  size_t e0 = idx * 8;
  size_t m = e0 >> 10;
  int c = (int)(e0 & 1023);
  const float* src;
  if (c < 256)      src = Mf  + m * 256 + c;
  else if (c < 512) src = DTf + m * 256 + (c - 256);
  else              src = Df  + m * 512 + (c - 512);
  float4 f0 = reinterpret_cast<const float4*>(src)[0];
  float4 f1 = reinterpret_cast<const float4*>(src)[1];
  uint4 o;
  o.x = pk2(f0.x, f0.y); o.y = pk2(f0.z, f0.w);
  o.z = pk2(f1.x, f1.y); o.w = pk2(f1.z, f1.w);
  *reinterpret_cast<uint4*>(ins + e0) = o;
}

__global__ void cast_w_kernel(const float* __restrict__ in, unsigned short* __restrict__ out, int n8) {
  int idx = blockIdx.x * blockDim.x + threadIdx.x;
  if (idx >= n8) return;
  const float* src = in + (size_t)idx * 8;
  float4 f0 = reinterpret_cast<const float4*>(src)[0];
  float4 f1 = reinterpret_cast<const float4*>(src)[1];
  uint4 o;
  o.x = pk2(f0.x, f0.y); o.y = pk2(f0.z, f0.w);
  o.z = pk2(f1.x, f1.y); o.w = pk2(f1.z, f1.w);
  *reinterpret_cast<uint4*>(out + (size_t)idx * 8) = o;
}

// ---------- GEMM (m97 structure, unchanged) ----------
template <int RELU, typename TOUT>
__global__ __launch_bounds__(256) void gemm_bt_kernel(const unsigned short* __restrict__ A,
                                                      const unsigned short* __restrict__ Bt,
                                                      TOUT* __restrict__ C,
                                                      int M, int N, int K) {
  __shared__ unsigned short As[128 * 32];
  __shared__ unsigned short Bs[128 * 32];
  const int tid = threadIdx.x;
  const int l = tid & 63, w = tid >> 6;
  const int lr = l & 15, lg = l >> 4;
  const int wm = w >> 1, wn = w & 1;
  const int tiles_n = N >> 7;
  const int tm = blockIdx.x / tiles_n, tn = blockIdx.x % tiles_n;
  const int bm0 = tm << 7, bn0 = tn << 7;

  f32x4 acc[4][4] = {};

  for (int kt = 0; kt < K; kt += 32) {
#pragma unroll
    for (int i = 0; i < 2; ++i) {
      int ch = tid + (i << 8);
      int row = ch >> 2, cc = ch & 3;
      const unsigned short* ga = A + (size_t)(bm0 + row) * K + kt + cc * 8;
      const unsigned short* gb = Bt + (size_t)(bn0 + row) * K + kt + cc * 8;
      unsigned short* la = As + ((size_t)((i << 8) + (w << 6))) * 8;
      unsigned short* lb = Bs + ((size_t)((i << 8) + (w << 6))) * 8;
      gload_lds16(ga, la);
      gload_lds16(gb, lb);
    }
    __syncthreads();
    short8 af[4], bf[4];
#pragma unroll
    for (int mi = 0; mi < 4; ++mi)
      af[mi] = *reinterpret_cast<const short8*>(As + (wm * 64 + mi * 16 + lr) * 32 + lg * 8);
#pragma unroll
    for (int ni = 0; ni < 4; ++ni)
      bf[ni] = *reinterpret_cast<const short8*>(Bs + (wn * 64 + ni * 16 + lr) * 32 + lg * 8);
#pragma unroll
    for (int mi = 0; mi < 4; ++mi)
#pragma unroll
      for (int ni = 0; ni < 4; ++ni)
        acc[mi][ni] = __builtin_amdgcn_mfma_f32_16x16x32_bf16(af[mi], bf[ni], acc[mi][ni], 0, 0, 0);
    __syncthreads();
  }

#pragma unroll
  for (int mi = 0; mi < 4; ++mi)
#pragma unroll
    for (int ni = 0; ni < 4; ++ni)
#pragma unroll
      for (int r = 0; r < 4; ++r) {
        int row = bm0 + wm * 64 + mi * 16 + lg * 4 + r;
        int col = bn0 + wn * 64 + ni * 16 + lr;
        float v = acc[mi][ni][r];
        if (RELU) v = fmaxf(v, 0.f);
        if constexpr (sizeof(TOUT) == 2) {
          reinterpret_cast<unsigned short*>(C)[(size_t)row * N + col] = f2bu(v);
        } else {
          C[(size_t)row * N + col] = v;
        }
      }
}

// ---------- xex init: publish swizzled bf16 image of x_0, set flags=1 ----------
// image layout per group g: 16 rows x 1KB; byte(row, k) = row*1024 + ((2k) ^ ((row&7)<<4))
__global__ void xex_init_kernel(const float* __restrict__ x0,
                                unsigned short* __restrict__ xex,
                                int* __restrict__ flags) {
  int g = blockIdx.x;          // 16 groups
  int tid = threadIdx.x;       // 256
#pragma unroll
  for (int c = 0; c < 4; ++c) {
    int idx = tid + c * 256;               // 0..1023
    int row = idx >> 6;                    // 0..15
    int kc = (idx & 63) << 3;              // col chunk of 8
    const float* src = x0 + (size_t)(g * 16 + row) * 512 + kc;
    float4 f0 = reinterpret_cast<const float4*>(src)[0];
    float4 f1 = reinterpret_cast<const float4*>(src)[1];
    uint4 o;
    o.x = pk2(f0.x, f0.y); o.y = pk2(f0.z, f0.w);
    o.z = pk2(f1.x, f1.y); o.w = pk2(f1.z, f1.w);
    *reinterpret_cast<uint4*>((char*)xex + g * 16384 + row * 1024 +
                              ((2 * kc) ^ ((row & 7) << 4))) = o;
  }
  if (g == 0 && tid < 64) flags[tid * 32] = 1;   // x_0 published
}

// ---------- recurrence, j-split: 64 blocks = 16 groups x 4 quarters ----------
// Block (g,q): W rows [128q,128q+128) LDS-resident (128KB, swizzled); per step
// computes y[16 rows][128 cols] = relu(G + x W^T), publishes bf16 slice into
// xex[(t+1)&1] (pre-swizzled image) and releases flag (monotonic counter).
__global__ __launch_bounds__(256)
void recurrence_j4(const float* __restrict__ Whh1,
                   const float* __restrict__ G,
                   unsigned short* xex,       // [2][16][16KB images]
                   int* flags,                // [64] stride-32 ints
                   float* __restrict__ X, float* __restrict__ Y) {
  __shared__ char smem[147456];   // [0,128K): W image; [128K,144K): x tile
  const int tid = threadIdx.x;
  const int l = tid & 63, wv = tid >> 6;      // 4 waves
  const int lr = l & 15, lg = l >> 4;
  const int g = blockIdx.x >> 2, q = blockIdx.x & 3;
  const int r0 = g << 4;
  const int jbw = wv << 5;                    // wave's 32-col window within 128
  char* Wl = smem;
  char* xls = smem + 131072;

  // ---- one-time: build swizzled W-quarter image in LDS ----
  {
    int j = tid >> 1;                 // 0..127 local row
    int kc0 = (tid & 1) << 8;         // 0 or 256
    const float* wr = Whh1 + (size_t)(128 * q + j) * 512 + kc0;
    int sw = (j & 7) << 4;
    for (int kk = 0; kk < 256; kk += 8) {
      float4 f0 = reinterpret_cast<const float4*>(wr + kk)[0];
      float4 f1 = reinterpret_cast<const float4*>(wr + kk)[1];
      uint4 o;
      o.x = pk2(f0.x, f0.y); o.y = pk2(f0.z, f0.w);
      o.z = pk2(f1.x, f1.y); o.w = pk2(f1.z, f1.w);
      *reinterpret_cast<uint4*>(Wl + j * 1024 + ((2 * (kc0 + kk)) ^ sw)) = o;
    }
  }
  __syncthreads();

  // G for t=0
  float gcur[2][4], gnxt[2][4];
#pragma unroll
  for (int jt = 0; jt < 2; ++jt)
#pragma unroll
    for (int r = 0; r < 4; ++r)
      gcur[jt][r] = G[((size_t)0 + r0 + lg * 4 + r) * 512 + q * 128 + jbw + jt * 16 + lr];

  const int f0i = (g * 4 + 0) * 32, f1i = (g * 4 + 1) * 32,
            f2i = (g * 4 + 2) * 32, f3i = (g * 4 + 3) * 32;
  const int myf = (g * 4 + q) * 32;

  for (int t = 0; t < 256; ++t) {
    // ---- wait for all 4 quarter-slices of x_t ----
    for (;;) {
      int v0 = __hip_atomic_load(&flags[f0i], __ATOMIC_RELAXED, __HIP_MEMORY_SCOPE_AGENT);
      int v1 = __hip_atomic_load(&flags[f1i], __ATOMIC_RELAXED, __HIP_MEMORY_SCOPE_AGENT);
      int v2 = __hip_atomic_load(&flags[f2i], __ATOMIC_RELAXED, __HIP_MEMORY_SCOPE_AGENT);
      int v3 = __hip_atomic_load(&flags[f3i], __ATOMIC_RELAXED, __HIP_MEMORY_SCOPE_AGENT);
      if (min(min(v0, v1), min(v2, v3)) >= t + 1) break;
      __builtin_amdgcn_s_sleep(2);
    }
    __builtin_amdgcn_fence(__ATOMIC_ACQUIRE, "agent");

    // ---- DMA x_t image into LDS (4 rows per wave, linear copy of the image) ----
    {
      const char* xsrc = (const char*)xex + (((t & 1) * 16 + g) * 16384);
#pragma unroll
      for (int rr = 0; rr < 4; ++rr) {
        int row = wv * 4 + rr;
        gload_lds16(xsrc + row * 1024 + l * 16, xls + row * 1024);
      }
    }
    __syncthreads();   // drains vmcnt; x tile ready for all waves

    // ---- A fragments ----
    short8 a[16];
#pragma unroll
    for (int kk = 0; kk < 16; ++kk)
      a[kk] = *reinterpret_cast<const short8*>(
          xls + lr * 1024 + ((kk * 64 + lg * 16) ^ ((lr & 7) << 4)));

    // ---- G prefetch for t+1 (hidden under MFMA) ----
    {
      int tn = (t < 255) ? t + 1 : t;
      const float* Gn = G + ((size_t)tn * 256 + r0) * 512;
#pragma unroll
      for (int jt = 0; jt < 2; ++jt)
#pragma unroll
        for (int r = 0; r < 4; ++r)
          gnxt[jt][r] = Gn[(lg * 4 + r) * 512 + q * 128 + jbw + jt * 16 + lr];
    }

    // ---- 32 MFMA from LDS-resident W ----
    f32x4 acc[2] = {};
#pragma unroll
    for (int jt = 0; jt < 2; ++jt) {
      int jl = jbw + jt * 16 + lr;
      const char* wbase = Wl + jl * 1024;
      int swj = (jl & 7) << 4;
#pragma unroll
      for (int kk = 0; kk < 16; ++kk) {
        short8 wf = *reinterpret_cast<const short8*>(wbase + ((kk * 64 + lg * 16) ^ swj));
        acc[jt] = __builtin_amdgcn_mfma_f32_16x16x32_bf16(a[kk], wf, acc[jt], 0, 0, 0);
      }
    }

    // ---- epilogue: X (f32), xex slice (bf16, pre-swizzled image), Y ----
    {
      char* xd = (char*)xex + ((((t + 1) & 1) * 16 + g) * 16384);
#pragma unroll
      for (int jt = 0; jt < 2; ++jt)
#pragma unroll
        for (int r = 0; r < 4; ++r) {
          float v = fmaxf(gcur[jt][r] + acc[jt][r], 0.f);
          int i = lg * 4 + r;
          int jc = jbw + jt * 16 + lr;       // local col in [0,128)
          int j = q * 128 + jc;              // global col
          X[((size_t)t * 256 + r0 + i) * 512 + j] = v;
          float vn = __shfl_xor(v, 1);
          if (!(lr & 1)) {
            *reinterpret_cast<unsigned int*>(
                xd + i * 1024 + (q << 8) + ((2 * jc) ^ ((i & 7) << 4))) = pk2(v, vn);
          }
          if (q == 3 && wv == 3 && jt == 1 && lr == 15) Y[t * 256 + r0 + i] = v;
        }
#pragma unroll
      for (int jt = 0; jt < 2; ++jt)
#pragma unroll
        for (int r = 0; r < 4; ++r) gcur[jt][r] = gnxt[jt][r];
    }

    __syncthreads();   // all waves: stores retired (vmcnt 0) + done reading x tile
    if (tid == 0 && t < 255)
      __hip_atomic_store(&flags[myf], t + 2, __ATOMIC_RELEASE, __HIP_MEMORY_SCOPE_AGENT);
  }
}

// ---------- launch ----------
extern "C" void kernel_launch(void* const* d_in, const int* in_sizes, int n_in,
                              void* d_out, int out_size, void* d_ws, size_t ws_size,
                              hipStream_t stream) {
  const float* x0   = (const float*)d_in[0];
  const float* Mf   = (const float*)d_in[1];
  const float* DTf  = (const float*)d_in[2];
  const float* Df   = (const float*)d_in[3];
  const float* Wih0 = (const float*)d_in[4];
  const float* Wih1 = (const float*)d_in[6];
  const float* Whh1 = (const float*)d_in[7];

  char* ws = (char*)d_ws;
  unsigned short* ins = (unsigned short*)(ws);
  unsigned short* H   = (unsigned short*)(ws + 134217728ULL);
  unsigned short* w0b = (unsigned short*)(ws + 268435456ULL);
  unsigned short* w1b = (unsigned short*)(ws + 270532608ULL);
  unsigned short* xex = (unsigned short*)(ws + 271581184ULL);  // 512KB: 2 x 16 x 16KB
  int* flags          = (int*)(ws + 272105472ULL);             // 64 x 128B
  float* G = (float*)(ws);   // aliases ins (dead after GEMM1)

  cast_concat_kernel<<<32768, 256, 0, stream>>>(Mf, DTf, Df, ins);
  cast_w_kernel<<<512, 256, 0, stream>>>(Wih0, w0b, 131072);
  cast_w_kernel<<<256, 256, 0, stream>>>(Wih1, w1b, 65536);

  gemm_bt_kernel<1, unsigned short><<<(65536 / 128) * (1024 / 128), 256, 0, stream>>>(
      ins, w0b, H, 65536, 1024, 1024);
  gemm_bt_kernel<0, float><<<(65536 / 128) * (512 / 128), 256, 0, stream>>>(
      H, w1b, G, 65536, 512, 1024);

  xex_init_kernel<<<16, 256, 0, stream>>>(x0, xex, flags);

  float* X = (float*)d_out;
  float* Y = X + 33554432;
  recurrence_j4<<<64, 256, 0, stream>>>(Whh1, G, xex, flags, X, Y);
}

// Round 5
// 1582.466 us; speedup vs baseline: 3.8353x; 1.1774x over previous
//
#include <hip/hip_runtime.h>

typedef __attribute__((ext_vector_type(8))) short short8;
typedef __attribute__((ext_vector_type(4))) float f32x4;

// ---------- helpers ----------
__device__ __forceinline__ unsigned short f2bu(float x) {
  unsigned int u = __float_as_uint(x);
  u += 0x7fffu + ((u >> 16) & 1u);
  return (unsigned short)(u >> 16);
}
__device__ __forceinline__ unsigned int pk2(float a, float b) {
  return (unsigned int)f2bu(a) | ((unsigned int)f2bu(b) << 16);
}
__device__ __forceinline__ void gload_lds16(const void* g, void* l) {
  __builtin_amdgcn_global_load_lds((const __attribute__((address_space(1))) unsigned int*)g,
                                   (__attribute__((address_space(3))) unsigned int*)l, 16, 0, 0);
}

// ---------- cast & concat ----------
__global__ void cast_concat_kernel(const float* __restrict__ Mf,
                                   const float* __restrict__ DTf,
                                   const float* __restrict__ Df,
                                   unsigned short* __restrict__ ins) {
  size_t idx = (size_t)blockIdx.x * blockDim.x + threadIdx.x;
  size_t e0 = idx * 8;
  size_t m = e0 >> 10;
  int c = (int)(e0 & 1023);
  const float* src;
  if (c < 256)      src = Mf  + m * 256 + c;
  else if (c < 512) src = DTf + m * 256 + (c - 256);
  else              src = Df  + m * 512 + (c - 512);
  float4 f0 = reinterpret_cast<const float4*>(src)[0];
  float4 f1 = reinterpret_cast<const float4*>(src)[1];
  uint4 o;
  o.x = pk2(f0.x, f0.y); o.y = pk2(f0.z, f0.w);
  o.z = pk2(f1.x, f1.y); o.w = pk2(f1.z, f1.w);
  *reinterpret_cast<uint4*>(ins + e0) = o;
}

__global__ void cast_w_kernel(const float* __restrict__ in, unsigned short* __restrict__ out, int n8) {
  int idx = blockIdx.x * blockDim.x + threadIdx.x;
  if (idx >= n8) return;
  const float* src = in + (size_t)idx * 8;
  float4 f0 = reinterpret_cast<const float4*>(src)[0];
  float4 f1 = reinterpret_cast<const float4*>(src)[1];
  uint4 o;
  o.x = pk2(f0.x, f0.y); o.y = pk2(f0.z, f0.w);
  o.z = pk2(f1.x, f1.y); o.w = pk2(f1.z, f1.w);
  *reinterpret_cast<uint4*>(out + (size_t)idx * 8) = o;
}

// ---------- GEMM (m97 structure, unchanged) ----------
template <int RELU, typename TOUT>
__global__ __launch_bounds__(256) void gemm_bt_kernel(const unsigned short* __restrict__ A,
                                                      const unsigned short* __restrict__ Bt,
                                                      TOUT* __restrict__ C,
                                                      int M, int N, int K) {
  __shared__ unsigned short As[128 * 32];
  __shared__ unsigned short Bs[128 * 32];
  const int tid = threadIdx.x;
  const int l = tid & 63, w = tid >> 6;
  const int lr = l & 15, lg = l >> 4;
  const int wm = w >> 1, wn = w & 1;
  const int tiles_n = N >> 7;
  const int tm = blockIdx.x / tiles_n, tn = blockIdx.x % tiles_n;
  const int bm0 = tm << 7, bn0 = tn << 7;

  f32x4 acc[4][4] = {};

  for (int kt = 0; kt < K; kt += 32) {
#pragma unroll
    for (int i = 0; i < 2; ++i) {
      int ch = tid + (i << 8);
      int row = ch >> 2, cc = ch & 3;
      const unsigned short* ga = A + (size_t)(bm0 + row) * K + kt + cc * 8;
      const unsigned short* gb = Bt + (size_t)(bn0 + row) * K + kt + cc * 8;
      unsigned short* la = As + ((size_t)((i << 8) + (w << 6))) * 8;
      unsigned short* lb = Bs + ((size_t)((i << 8) + (w << 6))) * 8;
      gload_lds16(ga, la);
      gload_lds16(gb, lb);
    }
    __syncthreads();
    short8 af[4], bf[4];
#pragma unroll
    for (int mi = 0; mi < 4; ++mi)
      af[mi] = *reinterpret_cast<const short8*>(As + (wm * 64 + mi * 16 + lr) * 32 + lg * 8);
#pragma unroll
    for (int ni = 0; ni < 4; ++ni)
      bf[ni] = *reinterpret_cast<const short8*>(Bs + (wn * 64 + ni * 16 + lr) * 32 + lg * 8);
#pragma unroll
    for (int mi = 0; mi < 4; ++mi)
#pragma unroll
      for (int ni = 0; ni < 4; ++ni)
        acc[mi][ni] = __builtin_amdgcn_mfma_f32_16x16x32_bf16(af[mi], bf[ni], acc[mi][ni], 0, 0, 0);
    __syncthreads();
  }

#pragma unroll
  for (int mi = 0; mi < 4; ++mi)
#pragma unroll
    for (int ni = 0; ni < 4; ++ni)
#pragma unroll
      for (int r = 0; r < 4; ++r) {
        int row = bm0 + wm * 64 + mi * 16 + lg * 4 + r;
        int col = bn0 + wn * 64 + ni * 16 + lr;
        float v = acc[mi][ni][r];
        if (RELU) v = fmaxf(v, 0.f);
        if constexpr (sizeof(TOUT) == 2) {
          reinterpret_cast<unsigned short*>(C)[(size_t)row * N + col] = f2bu(v);
        } else {
          C[(size_t)row * N + col] = v;
        }
      }
}

// ---------- recurrence, j-split, own-quarter-local + deferred stores ----------
// 64 blocks = 16 groups x 4 quarters. Block (g,q): W rows [128q,128q+128)
// LDS-resident. x image is quarter-major: [4 quarters][16 rows][256B], byte =
// qq*4096 + row*256 + ((2*klocal) ^ ((row&7)<<4)). Own slice written locally
// (LDS) + published to xex (agent write-through); remote 3 slices via
// global_load_lds after flag poll + acquire fence. X/Y stores deferred one
// step (issued post-fence, overlapping DMA).
__global__ __launch_bounds__(256)
void recurrence_j4(const float* __restrict__ Whh1,
                   const float* __restrict__ x0,
                   const float* __restrict__ G,
                   unsigned short* xex,       // [2][16 groups][4][4096B]
                   int* flags,                // [64] stride-32 ints
                   float* X, float* Y) {
  __shared__ char smem[163840];   // [0,128K) W; [128K,144K) xls0; [144K,160K) xls1
  const int tid = threadIdx.x;
  const int l = tid & 63, wv = tid >> 6;      // 4 waves
  const int lr = l & 15, lg = l >> 4;
  const int g = blockIdx.x >> 2, q = blockIdx.x & 3;
  const int r0 = g << 4;
  const int jbw = wv << 5;
  char* Wl = smem;
  char* xls0 = smem + 131072;
  char* xls1 = smem + 147456;

  // ---- one-time: swizzled W-quarter image ----
  {
    int j = tid >> 1;
    int kc0 = (tid & 1) << 8;
    const float* wr = Whh1 + (size_t)(128 * q + j) * 512 + kc0;
    int sw = (j & 7) << 4;
    for (int kk = 0; kk < 256; kk += 8) {
      float4 f0 = reinterpret_cast<const float4*>(wr + kk)[0];
      float4 f1 = reinterpret_cast<const float4*>(wr + kk)[1];
      uint4 o;
      o.x = pk2(f0.x, f0.y); o.y = pk2(f0.z, f0.w);
      o.z = pk2(f1.x, f1.y); o.w = pk2(f1.z, f1.w);
      *reinterpret_cast<uint4*>(Wl + j * 1024 + ((2 * (kc0 + kk)) ^ sw)) = o;
    }
  }
  // ---- one-time: full x_0 image (quarter-major) into xls0 ----
#pragma unroll
  for (int c = 0; c < 4; ++c) {
    int id = tid + (c << 8);
    int row = id >> 6;
    int kc = (id & 63) << 3;         // global col, step 8
    int qq = kc >> 7, kp = kc & 127;
    const float* src = x0 + (size_t)(r0 + row) * 512 + kc;
    float4 f0 = reinterpret_cast<const float4*>(src)[0];
    float4 f1 = reinterpret_cast<const float4*>(src)[1];
    uint4 o;
    o.x = pk2(f0.x, f0.y); o.y = pk2(f0.z, f0.w);
    o.z = pk2(f1.x, f1.y); o.w = pk2(f1.z, f1.w);
    *reinterpret_cast<uint4*>(xls0 + qq * 4096 + row * 256 +
                              ((2 * kp) ^ ((row & 7) << 4))) = o;
  }

  // G for t=0
  float gcur[8], gnxt[8];
#pragma unroll
  for (int jt = 0; jt < 2; ++jt)
#pragma unroll
    for (int r = 0; r < 4; ++r)
      gcur[jt * 4 + r] = G[((size_t)r0 + lg * 4 + r) * 512 + q * 128 + jbw + jt * 16 + lr];
  __syncthreads();

  const int swzR = (lr & 7) << 4;
  int rq[3], fqi[3];
  {
    int n = 0;
    for (int qq = 0; qq < 4; ++qq)
      if (qq != q) { rq[n] = qq; fqi[n] = (g * 4 + qq) * 32; ++n; }
  }
  const int myf = (g * 4 + q) * 32;
  float vsave[8];

  for (int t = 0; t < 256; ++t) {
    char* xc = (t & 1) ? xls1 : xls0;

    // ---- phase A: own-quarter MFMAs (local data, overlaps remote producers) ----
    f32x4 acc[2] = {};
    {
      short8 ao[4];
#pragma unroll
      for (int kp = 0; kp < 4; ++kp)
        ao[kp] = *reinterpret_cast<const short8*>(
            xc + q * 4096 + lr * 256 + ((kp * 64 + lg * 16) ^ swzR));
#pragma unroll
      for (int jt = 0; jt < 2; ++jt) {
        int jl = jbw + jt * 16 + lr;
        const char* wb = Wl + jl * 1024;
        int swj = (jl & 7) << 4;
#pragma unroll
        for (int kp = 0; kp < 4; ++kp) {
          short8 wf = *reinterpret_cast<const short8*>(
              wb + (((q * 4 + kp) * 64 + lg * 16) ^ swj));
          acc[jt] = __builtin_amdgcn_mfma_f32_16x16x32_bf16(ao[kp], wf, acc[jt], 0, 0, 0);
        }
      }
    }

    // ---- phase B: poll remote flags, fence, DMA remote slices, deferred X/Y, G pref ----
    if (t) {
      for (;;) {
        int v0 = __hip_atomic_load(&flags[fqi[0]], __ATOMIC_RELAXED, __HIP_MEMORY_SCOPE_AGENT);
        int v1 = __hip_atomic_load(&flags[fqi[1]], __ATOMIC_RELAXED, __HIP_MEMORY_SCOPE_AGENT);
        int v2 = __hip_atomic_load(&flags[fqi[2]], __ATOMIC_RELAXED, __HIP_MEMORY_SCOPE_AGENT);
        if (min(min(v0, v1), v2) >= t) break;
        __builtin_amdgcn_s_sleep(1);
      }
      __builtin_amdgcn_fence(__ATOMIC_ACQUIRE, "agent");
      const char* xsb = (const char*)xex + (((t & 1) * 16 + g) * 16384);
#pragma unroll
      for (int m = 0; m < 3; ++m)
        gload_lds16(xsb + rq[m] * 4096 + wv * 1024 + (size_t)l * 16,
                    xc + rq[m] * 4096 + wv * 1024);
      // deferred X/Y for step t-1 (write-through, fire-and-forget)
      {
        float* Xp = X + ((size_t)(t - 1) * 256 + r0) * 512 + q * 128;
#pragma unroll
        for (int jt = 0; jt < 2; ++jt)
#pragma unroll
          for (int r = 0; r < 4; ++r)
            __hip_atomic_store(&Xp[(size_t)(lg * 4 + r) * 512 + jbw + jt * 16 + lr],
                               vsave[jt * 4 + r], __ATOMIC_RELAXED, __HIP_MEMORY_SCOPE_AGENT);
        if (q == 3 && wv == 3 && lr == 15)
#pragma unroll
          for (int r = 0; r < 4; ++r)
            __hip_atomic_store(&Y[(t - 1) * 256 + r0 + lg * 4 + r], vsave[4 + r],
                               __ATOMIC_RELAXED, __HIP_MEMORY_SCOPE_AGENT);
      }
      // G prefetch for t+1
      {
        int tn = (t < 255) ? t + 1 : t;
        const float* Gn = G + ((size_t)tn * 256 + r0) * 512 + q * 128;
#pragma unroll
        for (int jt = 0; jt < 2; ++jt)
#pragma unroll
          for (int r = 0; r < 4; ++r)
            gnxt[jt * 4 + r] = Gn[(size_t)(lg * 4 + r) * 512 + jbw + jt * 16 + lr];
      }
      __syncthreads();   // drains vmcnt: DMA complete, x tile ready
    } else {
      const float* Gn = G + ((size_t)1 * 256 + r0) * 512 + q * 128;
#pragma unroll
      for (int jt = 0; jt < 2; ++jt)
#pragma unroll
        for (int r = 0; r < 4; ++r)
          gnxt[jt * 4 + r] = Gn[(size_t)(lg * 4 + r) * 512 + jbw + jt * 16 + lr];
    }

    // ---- phase C: remote-quarter MFMAs ----
#pragma unroll
    for (int m = 0; m < 3; ++m) {
      int qq = rq[m];
      short8 ar[4];
#pragma unroll
      for (int kp = 0; kp < 4; ++kp)
        ar[kp] = *reinterpret_cast<const short8*>(
            xc + qq * 4096 + lr * 256 + ((kp * 64 + lg * 16) ^ swzR));
#pragma unroll
      for (int jt = 0; jt < 2; ++jt) {
        int jl = jbw + jt * 16 + lr;
        const char* wb = Wl + jl * 1024;
        int swj = (jl & 7) << 4;
#pragma unroll
        for (int kp = 0; kp < 4; ++kp) {
          short8 wf = *reinterpret_cast<const short8*>(
              wb + (((qq * 4 + kp) * 64 + lg * 16) ^ swj));
          acc[jt] = __builtin_amdgcn_mfma_f32_16x16x32_bf16(ar[kp], wf, acc[jt], 0, 0, 0);
        }
      }
    }

    // ---- phase D: epilogue ----
#pragma unroll
    for (int jt = 0; jt < 2; ++jt)
#pragma unroll
      for (int r = 0; r < 4; ++r)
        vsave[jt * 4 + r] = fmaxf(gcur[jt * 4 + r] + acc[jt][r], 0.f);
#pragma unroll
    for (int e = 0; e < 8; ++e) gcur[e] = gnxt[e];

    if (t < 255) {
      char* xn = (t & 1) ? xls0 : xls1;
      char* xd = (char*)xex + ((((t + 1) & 1) * 16 + g) * 16384) + q * 4096;
#pragma unroll
      for (int jt = 0; jt < 2; ++jt)
#pragma unroll
        for (int r = 0; r < 4; ++r) {
          float v = vsave[jt * 4 + r];
          float vn = __shfl_xor(v, 1);
          if (!(lr & 1)) {
            int i = lg * 4 + r;
            int jc = jbw + jt * 16 + lr;
            int off = i * 256 + ((2 * jc) ^ ((i & 7) << 4));
            unsigned int pv = pk2(v, vn);
            *reinterpret_cast<unsigned int*>(xn + q * 4096 + off) = pv;          // LDS
            __hip_atomic_store((unsigned int*)(xd + off), pv,
                               __ATOMIC_RELAXED, __HIP_MEMORY_SCOPE_AGENT);      // publish
          }
        }
      asm volatile("s_waitcnt vmcnt(0) lgkmcnt(0)" ::: "memory");
      __builtin_amdgcn_s_barrier();
      if (tid == 0)
        __hip_atomic_store(&flags[myf], t + 1, __ATOMIC_RELEASE, __HIP_MEMORY_SCOPE_AGENT);
    }
  }

  // final X/Y for t=255
  {
    float* Xp = X + ((size_t)255 * 256 + r0) * 512 + q * 128;
#pragma unroll
    for (int jt = 0; jt < 2; ++jt)
#pragma unroll
      for (int r = 0; r < 4; ++r)
        Xp[(size_t)(lg * 4 + r) * 512 + jbw + jt * 16 + lr] = vsave[jt * 4 + r];
    if (q == 3 && wv == 3 && lr == 15)
#pragma unroll
      for (int r = 0; r < 4; ++r)
        Y[255 * 256 + r0 + lg * 4 + r] = vsave[4 + r];
  }
}

// ---------- launch ----------
extern "C" void kernel_launch(void* const* d_in, const int* in_sizes, int n_in,
                              void* d_out, int out_size, void* d_ws, size_t ws_size,
                              hipStream_t stream) {
  const float* x0   = (const float*)d_in[0];
  const float* Mf   = (const float*)d_in[1];
  const float* DTf  = (const float*)d_in[2];
  const float* Df   = (const float*)d_in[3];
  const float* Wih0 = (const float*)d_in[4];
  const float* Wih1 = (const float*)d_in[6];
  const float* Whh1 = (const float*)d_in[7];

  char* ws = (char*)d_ws;
  unsigned short* ins = (unsigned short*)(ws);
  unsigned short* H   = (unsigned short*)(ws + 134217728ULL);
  unsigned short* w0b = (unsigned short*)(ws + 268435456ULL);
  unsigned short* w1b = (unsigned short*)(ws + 270532608ULL);
  unsigned short* xex = (unsigned short*)(ws + 271581184ULL);  // 512KB
  int* flags          = (int*)(ws + 272105472ULL);             // 8KB
  float* G = (float*)(ws);   // aliases ins (dead after GEMM1)

  hipMemsetAsync(flags, 0, 8192, stream);
  cast_concat_kernel<<<32768, 256, 0, stream>>>(Mf, DTf, Df, ins);
  cast_w_kernel<<<512, 256, 0, stream>>>(Wih0, w0b, 131072);
  cast_w_kernel<<<256, 256, 0, stream>>>(Wih1, w1b, 65536);

  gemm_bt_kernel<1, unsigned short><<<(65536 / 128) * (1024 / 128), 256, 0, stream>>>(
      ins, w0b, H, 65536, 1024, 1024);
  gemm_bt_kernel<0, float><<<(65536 / 128) * (512 / 128), 256, 0, stream>>>(
      H, w1b, G, 65536, 512, 1024);

  float* X = (float*)d_out;
  float* Y = X + 33554432;
  recurrence_j4<<<64, 256, 0, stream>>>(Whh1, x0, G, xex, flags, X, Y);
}

// Round 7
// 1525.618 us; speedup vs baseline: 3.9782x; 1.0373x over previous
//
#include <hip/hip_runtime.h>

typedef __attribute__((ext_vector_type(8))) short short8;
typedef __attribute__((ext_vector_type(4))) float f32x4;
typedef __attribute__((ext_vector_type(4))) unsigned int u32x4;

// ---------- helpers ----------
__device__ __forceinline__ unsigned short f2bu(float x) {
  unsigned int u = __float_as_uint(x);
  u += 0x7fffu + ((u >> 16) & 1u);
  return (unsigned short)(u >> 16);
}
__device__ __forceinline__ unsigned int pk2(float a, float b) {
  return (unsigned int)f2bu(a) | ((unsigned int)f2bu(b) << 16);
}
__device__ __forceinline__ void gload_lds16(const void* g, void* l) {
  __builtin_amdgcn_global_load_lds((const __attribute__((address_space(1))) unsigned int*)g,
                                   (__attribute__((address_space(3))) unsigned int*)l, 16, 0, 0);
}
__device__ __forceinline__ void store16_sc1(void* p, u32x4 v) {
  // agent-scope write-through store (updates to coherence point, keeps L2 clean)
  asm volatile("global_store_dwordx4 %0, %1, off sc1" :: "v"(p), "v"(v) : "memory");
}

// ---------- cast & concat ----------
__global__ void cast_concat_kernel(const float* __restrict__ Mf,
                                   const float* __restrict__ DTf,
                                   const float* __restrict__ Df,
                                   unsigned short* __restrict__ ins) {
  size_t idx = (size_t)blockIdx.x * blockDim.x + threadIdx.x;
  size_t e0 = idx * 8;
  size_t m = e0 >> 10;
  int c = (int)(e0 & 1023);
  const float* src;
  if (c < 256)      src = Mf  + m * 256 + c;
  else if (c < 512) src = DTf + m * 256 + (c - 256);
  else              src = Df  + m * 512 + (c - 512);
  float4 f0 = reinterpret_cast<const float4*>(src)[0];
  float4 f1 = reinterpret_cast<const float4*>(src)[1];
  uint4 o;
  o.x = pk2(f0.x, f0.y); o.y = pk2(f0.z, f0.w);
  o.z = pk2(f1.x, f1.y); o.w = pk2(f1.z, f1.w);
  *reinterpret_cast<uint4*>(ins + e0) = o;
}

__global__ void cast_w_kernel(const float* __restrict__ in, unsigned short* __restrict__ out, int n8) {
  int idx = blockIdx.x * blockDim.x + threadIdx.x;
  if (idx >= n8) return;
  const float* src = in + (size_t)idx * 8;
  float4 f0 = reinterpret_cast<const float4*>(src)[0];
  float4 f1 = reinterpret_cast<const float4*>(src)[1];
  uint4 o;
  o.x = pk2(f0.x, f0.y); o.y = pk2(f0.z, f0.w);
  o.z = pk2(f1.x, f1.y); o.w = pk2(f1.z, f1.w);
  *reinterpret_cast<uint4*>(out + (size_t)idx * 8) = o;
}

// ---------- GEMM (m97 structure, unchanged) ----------
template <int RELU, typename TOUT>
__global__ __launch_bounds__(256) void gemm_bt_kernel(const unsigned short* __restrict__ A,
                                                      const unsigned short* __restrict__ Bt,
                                                      TOUT* __restrict__ C,
                                                      int M, int N, int K) {
  __shared__ unsigned short As[128 * 32];
  __shared__ unsigned short Bs[128 * 32];
  const int tid = threadIdx.x;
  const int l = tid & 63, w = tid >> 6;
  const int lr = l & 15, lg = l >> 4;
  const int wm = w >> 1, wn = w & 1;
  const int tiles_n = N >> 7;
  const int tm = blockIdx.x / tiles_n, tn = blockIdx.x % tiles_n;
  const int bm0 = tm << 7, bn0 = tn << 7;

  f32x4 acc[4][4] = {};

  for (int kt = 0; kt < K; kt += 32) {
#pragma unroll
    for (int i = 0; i < 2; ++i) {
      int ch = tid + (i << 8);
      int row = ch >> 2, cc = ch & 3;
      const unsigned short* ga = A + (size_t)(bm0 + row) * K + kt + cc * 8;
      const unsigned short* gb = Bt + (size_t)(bn0 + row) * K + kt + cc * 8;
      unsigned short* la = As + ((size_t)((i << 8) + (w << 6))) * 8;
      unsigned short* lb = Bs + ((size_t)((i << 8) + (w << 6))) * 8;
      gload_lds16(ga, la);
      gload_lds16(gb, lb);
    }
    __syncthreads();
    short8 af[4], bf[4];
#pragma unroll
    for (int mi = 0; mi < 4; ++mi)
      af[mi] = *reinterpret_cast<const short8*>(As + (wm * 64 + mi * 16 + lr) * 32 + lg * 8);
#pragma unroll
    for (int ni = 0; ni < 4; ++ni)
      bf[ni] = *reinterpret_cast<const short8*>(Bs + (wn * 64 + ni * 16 + lr) * 32 + lg * 8);
#pragma unroll
    for (int mi = 0; mi < 4; ++mi)
#pragma unroll
      for (int ni = 0; ni < 4; ++ni)
        acc[mi][ni] = __builtin_amdgcn_mfma_f32_16x16x32_bf16(af[mi], bf[ni], acc[mi][ni], 0, 0, 0);
    __syncthreads();
  }

#pragma unroll
  for (int mi = 0; mi < 4; ++mi)
#pragma unroll
    for (int ni = 0; ni < 4; ++ni)
#pragma unroll
      for (int r = 0; r < 4; ++r) {
        int row = bm0 + wm * 64 + mi * 16 + lg * 4 + r;
        int col = bn0 + wn * 64 + ni * 16 + lr;
        float v = acc[mi][ni][r];
        if (RELU) v = fmaxf(v, 0.f);
        if constexpr (sizeof(TOUT) == 2) {
          reinterpret_cast<unsigned short*>(C)[(size_t)row * N + col] = f2bu(v);
        } else {
          C[(size_t)row * N + col] = v;
        }
      }
}

// ---------- recurrence, j-split, latency-overlapped schedule ----------
// 64 blocks = 16 groups x 4 quarters; group's 4 blocks co-located per XCD.
// Per step: [issue G-prefetch + deferred X/Y] || own-quarter MFMA || poll ->
// fence -> DMA remote slices -> remote MFMA -> epilogue (LDS only) ->
// readback + 1 coalesced sc1 store -> vmcnt(0) -> release flag.
__global__ __launch_bounds__(256)
void recurrence_j4(const float* __restrict__ Whh1,
                   const float* __restrict__ x0,
                   const float* __restrict__ G,
                   unsigned short* xex,       // [2][16 groups][4][4096B]
                   int* flags,                // [64] stride-32 ints
                   float* __restrict__ X, float* __restrict__ Y) {
  __shared__ char smem[163840];   // [0,128K) W; [128K,144K) xls0; [144K,160K) xls1
  const int tid = threadIdx.x;
  const int l = tid & 63, wv = tid >> 6;      // 4 waves
  const int lr = l & 15, lg = l >> 4;
  const int bid = blockIdx.x;
  const int g = ((bid & 7) << 1) | ((bid >> 3) & 1);   // XCD co-location
  const int q = bid >> 4;
  const int r0 = g << 4;
  const int jbw = wv << 5;
  char* Wl = smem;
  char* xls0 = smem + 131072;
  char* xls1 = smem + 147456;

  // ---- one-time: swizzled W-quarter image ----
  {
    int j = tid >> 1;
    int kc0 = (tid & 1) << 8;
    const float* wr = Whh1 + (size_t)(128 * q + j) * 512 + kc0;
    int sw = (j & 7) << 4;
    for (int kk = 0; kk < 256; kk += 8) {
      float4 f0 = reinterpret_cast<const float4*>(wr + kk)[0];
      float4 f1 = reinterpret_cast<const float4*>(wr + kk)[1];
      uint4 o;
      o.x = pk2(f0.x, f0.y); o.y = pk2(f0.z, f0.w);
      o.z = pk2(f1.x, f1.y); o.w = pk2(f1.z, f1.w);
      *reinterpret_cast<uint4*>(Wl + j * 1024 + ((2 * (kc0 + kk)) ^ sw)) = o;
    }
  }
  // ---- one-time: full x_0 image (quarter-major) into xls0 ----
#pragma unroll
  for (int c = 0; c < 4; ++c) {
    int id = tid + (c << 8);
    int row = id >> 6;
    int kc = (id & 63) << 3;
    int qq = kc >> 7, kp = kc & 127;
    const float* src = x0 + (size_t)(r0 + row) * 512 + kc;
    float4 f0 = reinterpret_cast<const float4*>(src)[0];
    float4 f1 = reinterpret_cast<const float4*>(src)[1];
    uint4 o;
    o.x = pk2(f0.x, f0.y); o.y = pk2(f0.z, f0.w);
    o.z = pk2(f1.x, f1.y); o.w = pk2(f1.z, f1.w);
    *reinterpret_cast<uint4*>(xls0 + qq * 4096 + row * 256 +
                              ((2 * kp) ^ ((row & 7) << 4))) = o;
  }

  // G for t=0
  float gcur[8], gnxt[8];
#pragma unroll
  for (int jt = 0; jt < 2; ++jt)
#pragma unroll
    for (int r = 0; r < 4; ++r)
      gcur[jt * 4 + r] = G[((size_t)r0 + lg * 4 + r) * 512 + q * 128 + jbw + jt * 16 + lr];
  __syncthreads();

  const int swzR = (lr & 7) << 4;
  int rq[3], fqi[3];
  {
    int n = 0;
    for (int qq = 0; qq < 4; ++qq)
      if (qq != q) { rq[n] = qq; fqi[n] = (g * 4 + qq) * 32; ++n; }
  }
  const int myf = (g * 4 + q) * 32;
  float vsave[8];

  for (int t = 0; t < 256; ++t) {
    char* xc = (t & 1) ? xls1 : xls0;

    // ---- phase 0: issue long-latency ops (independent of remote x_t) ----
    if (t) {
      // deferred X/Y for t-1: fire-and-forget, acks absorbed by poll wait
      float* Xp = X + ((size_t)(t - 1) * 256 + r0) * 512 + q * 128;
#pragma unroll
      for (int jt = 0; jt < 2; ++jt)
#pragma unroll
        for (int r = 0; r < 4; ++r)
          __hip_atomic_store(&Xp[(size_t)(lg * 4 + r) * 512 + jbw + jt * 16 + lr],
                             vsave[jt * 4 + r], __ATOMIC_RELAXED, __HIP_MEMORY_SCOPE_AGENT);
      if (q == 3 && wv == 3 && lr == 15)
#pragma unroll
        for (int r = 0; r < 4; ++r)
          __hip_atomic_store(&Y[(t - 1) * 256 + r0 + lg * 4 + r], vsave[4 + r],
                             __ATOMIC_RELAXED, __HIP_MEMORY_SCOPE_AGENT);
    }
    {
      // G prefetch for t+1: HBM latency hides under own-MFMA + poll
      int tn = (t < 255) ? t + 1 : t;
      const float* Gn = G + ((size_t)tn * 256 + r0) * 512 + q * 128;
#pragma unroll
      for (int jt = 0; jt < 2; ++jt)
#pragma unroll
        for (int r = 0; r < 4; ++r)
          gnxt[jt * 4 + r] = Gn[(size_t)(lg * 4 + r) * 512 + jbw + jt * 16 + lr];
    }

    // ---- phase A: own-quarter MFMAs (local LDS data) ----
    f32x4 acc[2] = {};
    {
      short8 ao[4];
#pragma unroll
      for (int kp = 0; kp < 4; ++kp)
        ao[kp] = *reinterpret_cast<const short8*>(
            xc + q * 4096 + lr * 256 + ((kp * 64 + lg * 16) ^ swzR));
#pragma unroll
      for (int jt = 0; jt < 2; ++jt) {
        int jl = jbw + jt * 16 + lr;
        const char* wb = Wl + jl * 1024;
        int swj = (jl & 7) << 4;
#pragma unroll
        for (int kp = 0; kp < 4; ++kp) {
          short8 wf = *reinterpret_cast<const short8*>(
              wb + (((q * 4 + kp) * 64 + lg * 16) ^ swj));
          acc[jt] = __builtin_amdgcn_mfma_f32_16x16x32_bf16(ao[kp], wf, acc[jt], 0, 0, 0);
        }
      }
    }

    // ---- phase B: poll, fence, DMA remote slices ----
    if (t) {
      for (;;) {
        int v0 = __hip_atomic_load(&flags[fqi[0]], __ATOMIC_RELAXED, __HIP_MEMORY_SCOPE_AGENT);
        int v1 = __hip_atomic_load(&flags[fqi[1]], __ATOMIC_RELAXED, __HIP_MEMORY_SCOPE_AGENT);
        int v2 = __hip_atomic_load(&flags[fqi[2]], __ATOMIC_RELAXED, __HIP_MEMORY_SCOPE_AGENT);
        if (min(min(v0, v1), v2) >= t) break;
      }
      __builtin_amdgcn_fence(__ATOMIC_ACQUIRE, "agent");
      const char* xsb = (const char*)xex + (((t & 1) * 16 + g) * 16384);
#pragma unroll
      for (int m = 0; m < 3; ++m)
        gload_lds16(xsb + rq[m] * 4096 + wv * 1024 + (size_t)l * 16,
                    xc + rq[m] * 4096 + wv * 1024);
      __syncthreads();   // drains vmcnt: DMA done (G loads already landed during poll)
    }

    // ---- phase C: remote-quarter MFMAs ----
#pragma unroll
    for (int m = 0; m < 3; ++m) {
      int qq = rq[m];
      short8 ar[4];
#pragma unroll
      for (int kp = 0; kp < 4; ++kp)
        ar[kp] = *reinterpret_cast<const short8*>(
            xc + qq * 4096 + lr * 256 + ((kp * 64 + lg * 16) ^ swzR));
#pragma unroll
      for (int jt = 0; jt < 2; ++jt) {
        int jl = jbw + jt * 16 + lr;
        const char* wb = Wl + jl * 1024;
        int swj = (jl & 7) << 4;
#pragma unroll
        for (int kp = 0; kp < 4; ++kp) {
          short8 wf = *reinterpret_cast<const short8*>(
              wb + (((qq * 4 + kp) * 64 + lg * 16) ^ swj));
          acc[jt] = __builtin_amdgcn_mfma_f32_16x16x32_bf16(ar[kp], wf, acc[jt], 0, 0, 0);
        }
      }
    }

    // ---- phase D: epilogue (regs + LDS only) ----
#pragma unroll
    for (int jt = 0; jt < 2; ++jt)
#pragma unroll
      for (int r = 0; r < 4; ++r)
        vsave[jt * 4 + r] = fmaxf(gcur[jt * 4 + r] + acc[jt][r], 0.f);
#pragma unroll
    for (int e = 0; e < 8; ++e) gcur[e] = gnxt[e];

    if (t < 255) {
      char* xn = (t & 1) ? xls0 : xls1;
#pragma unroll
      for (int jt = 0; jt < 2; ++jt)
#pragma unroll
        for (int r = 0; r < 4; ++r) {
          float v = vsave[jt * 4 + r];
          float vn = __shfl_xor(v, 1);
          if (!(lr & 1)) {
            int i = lg * 4 + r;
            int jc = jbw + jt * 16 + lr;
            *reinterpret_cast<unsigned int*>(
                xn + q * 4096 + i * 256 + ((2 * jc) ^ ((i & 7) << 4))) = pk2(v, vn);
          }
        }
      // ---- phase E: coalesced publish from LDS image + release ----
      __syncthreads();   // own slice complete in LDS
      char* xd = (char*)xex + ((((t + 1) & 1) * 16 + g) * 16384) + q * 4096;
      u32x4 val = *reinterpret_cast<const u32x4*>(xn + q * 4096 + tid * 16);
      store16_sc1(xd + tid * 16, val);
      asm volatile("s_waitcnt vmcnt(0)" ::: "memory");
      __builtin_amdgcn_s_barrier();   // all waves' publish acked
      if (tid == 0)
        __hip_atomic_store(&flags[myf], t + 1, __ATOMIC_RELEASE, __HIP_MEMORY_SCOPE_AGENT);
    }
  }

  // final X/Y for t=255
  {
    float* Xp = X + ((size_t)255 * 256 + r0) * 512 + q * 128;
#pragma unroll
    for (int jt = 0; jt < 2; ++jt)
#pragma unroll
      for (int r = 0; r < 4; ++r)
        Xp[(size_t)(lg * 4 + r) * 512 + jbw + jt * 16 + lr] = vsave[jt * 4 + r];
    if (q == 3 && wv == 3 && lr == 15)
#pragma unroll
      for (int r = 0; r < 4; ++r)
        Y[255 * 256 + r0 + lg * 4 + r] = vsave[4 + r];
  }
}

// ---------- launch ----------
extern "C" void kernel_launch(void* const* d_in, const int* in_sizes, int n_in,
                              void* d_out, int out_size, void* d_ws, size_t ws_size,
                              hipStream_t stream) {
  const float* x0   = (const float*)d_in[0];
  const float* Mf   = (const float*)d_in[1];
  const float* DTf  = (const float*)d_in[2];
  const float* Df   = (const float*)d_in[3];
  const float* Wih0 = (const float*)d_in[4];
  const float* Wih1 = (const float*)d_in[6];
  const float* Whh1 = (const float*)d_in[7];

  char* ws = (char*)d_ws;
  unsigned short* ins = (unsigned short*)(ws);
  unsigned short* H   = (unsigned short*)(ws + 134217728ULL);
  unsigned short* w0b = (unsigned short*)(ws + 268435456ULL);
  unsigned short* w1b = (unsigned short*)(ws + 270532608ULL);
  unsigned short* xex = (unsigned short*)(ws + 271581184ULL);  // 512KB
  int* flags          = (int*)(ws + 272105472ULL);             // 8KB
  float* G = (float*)(ws);   // aliases ins (dead after GEMM1)

  (void)hipMemsetAsync(flags, 0, 8192, stream);
  cast_concat_kernel<<<32768, 256, 0, stream>>>(Mf, DTf, Df, ins);
  cast_w_kernel<<<512, 256, 0, stream>>>(Wih0, w0b, 131072);
  cast_w_kernel<<<256, 256, 0, stream>>>(Wih1, w1b, 65536);

  gemm_bt_kernel<1, unsigned short><<<(65536 / 128) * (1024 / 128), 256, 0, stream>>>(
      ins, w0b, H, 65536, 1024, 1024);
  gemm_bt_kernel<0, float><<<(65536 / 128) * (512 / 128), 256, 0, stream>>>(
      H, w1b, G, 65536, 512, 1024);

  float* X = (float*)d_out;
  float* Y = X + 33554432;
  recurrence_j4<<<64, 256, 0, stream>>>(Whh1, x0, G, xex, flags, X, Y);
}